// Round 1
// baseline (365.379 us; speedup 1.0000x reference)
//
#include <hip/hip_runtime.h>
#include <hip/hip_bf16.h>
#include <cstdint>

typedef unsigned short u16;
typedef uint32_t u32;

constexpr int Tc = 512, Bc = 32, Vc = 4096, Sc = 128;
constexpr int BOOST = 13;    // per-step 2^13 boost folded into emissions (exactly accounted)
constexpr int BSTRIDE = 576; // blankT row stride (Tc + 64 slack)
constexpr float LOG2E = 1.4426950408889634f;
constexpr float LN2 = 0.6931471805599453f;
constexpr int NT = 4;        // t-rows gathered per wave (12 scattered loads in flight/wave)

__device__ __forceinline__ float bflo(u32 p) { return __uint_as_float(p << 16); }
__device__ __forceinline__ float bfhi(u32 p) { return __uint_as_float(p & 0xffff0000u); }

__device__ __forceinline__ u32 f2bf_bits(float f) {
    __hip_bfloat16 h = __float2bfloat16(f);
    return (u32)(*reinterpret_cast<u16*>(&h));
}

// readlane -> SGPR float (lane index is a compile-time constant after unroll)
#define RLF(v, i) __int_as_float(__builtin_amdgcn_readlane(__float_as_int(v), (i)))

// ---------------------------------------------------------------------------
// Kernel 1: direct per-lane gather. The old per-(t,b) dedupe (LDS bitmap +
// atomicOr + popc rank + 5 syncthreads + 8.3KB LDS round trip) fetched the
// same distinct 64B sectors the caches dedupe for free. Here: wave w of each
// 256-thread block owns NT=4 consecutive t-rows of batch b; lane l issues
// 3*NT scattered dword loads (tgt[2l], tgt[2l+1], blank - blank coalesces to
// a single broadcast request), waits once, then exp2+bf16-packs the 256B emit
// row and lane 0 stores the blank. No LDS, no atomics, no __syncthreads,
// ~192 outstanding 64B misses per CU at 16 waves/CU -> HBM-saturating.
// Math is bit-identical to the previous verified kernel.
// ---------------------------------------------------------------------------
__global__ __launch_bounds__(256) void k_gather(const float* __restrict__ lp,
                                                const int* __restrict__ tgt,
                                                u32* __restrict__ emitT,
                                                float* __restrict__ blankT) {
    const int b = blockIdx.y;
    const int lane = threadIdx.x & 63;
    const int wv = threadIdx.x >> 6;
    const int t0 = (blockIdx.x * 4 + wv) * NT;

    const int tg0 = tgt[b * Sc + 2 * lane];
    const int tg1 = tgt[b * Sc + 2 * lane + 1];

    const float* row0 = lp + ((size_t)t0 * Bc + b) * Vc;
    float v0[NT], v1[NT], vb[NT];
#pragma unroll
    for (int i = 0; i < NT; ++i) {
        const float* row = row0 + (size_t)i * (Bc * Vc);
        v0[i] = row[tg0];
        v1[i] = row[tg1];
        vb[i] = row[0];            // same addr across lanes -> one broadcast req
    }

    u32* orow = emitT + ((size_t)b * Tc + t0) * 64 + lane;
    float* bout = blankT + b * BSTRIDE + t0;
#pragma unroll
    for (int i = 0; i < NT; ++i) {
        const float e0 = __builtin_amdgcn_exp2f(fmaf(v0[i], LOG2E, (float)BOOST));
        const float e1 = __builtin_amdgcn_exp2f(fmaf(v1[i], LOG2E, (float)BOOST));
        orow[i * 64] = f2bf_bits(e0) | (f2bf_bits(e1) << 16);
        const float eb = __builtin_amdgcn_exp2f(fmaf(vb[i], LOG2E, (float)BOOST));
        if (lane == 0) bout[i] = eb;
    }
}

// ---------------------------------------------------------------------------
// DPP wave-max (64 lanes) -> broadcast via readlane 63.
// ---------------------------------------------------------------------------
template <int CTRL, int RMASK>
__device__ __forceinline__ float dppmax(float v) {
    int t = __builtin_amdgcn_update_dpp(__float_as_int(v), __float_as_int(v),
                                        CTRL, RMASK, 0xf, false);
    return fmaxf(v, __int_as_float(t));
}
__device__ __forceinline__ float wave_max_bcast(float v) {
    v = dppmax<0x111, 0xf>(v);   // row_shr:1
    v = dppmax<0x112, 0xf>(v);   // row_shr:2
    v = dppmax<0x114, 0xf>(v);   // row_shr:4
    v = dppmax<0x118, 0xf>(v);   // row_shr:8
    v = dppmax<0x142, 0xa>(v);   // row_bcast:15 -> rows 1,3
    v = dppmax<0x143, 0xc>(v);   // row_bcast:31 -> rows 2,3
    return __int_as_float(__builtin_amdgcn_readlane(__float_as_int(v), 63));
}

// wave-wide shift right by 1 lane; lane 0 receives 0 (bound_ctrl).
__device__ __forceinline__ float wave_shr1(float v) {
    return __int_as_float(__builtin_amdgcn_update_dpp(
        0, __float_as_int(v), 0x138, 0xf, 0xf, true));
}

// ---------------------------------------------------------------------------
// Kernel 2: linear-domain CTC alpha recursion, one wave per batch element.
// Lane l owns states 4l..4l+3; state 256 rides in a4 (lane 63). Blank stream:
// ONE lane-coalesced vector load per 64 steps + per-step v_readlane (no
// wave-uniform scalar loads -> no lgkmcnt(0)-per-step drain). Emit stream:
// 32-row-deep register prefetch (slot (t-1)&31, refill row t+32).
// Renormalize by an exact power of 2 every 8 steps.
// ---------------------------------------------------------------------------
__global__ __launch_bounds__(64) void k_ctc(const u32* __restrict__ emitT,
                                            const float* __restrict__ blankT,
                                            const int* __restrict__ tgt,
                                            const int* __restrict__ in_len,
                                            const int* __restrict__ tg_len,
                                            float* __restrict__ out) {
    const int b = blockIdx.x;
    const int lane = threadIdx.x;
    const u32* p = emitT + (size_t)b * Tc * 64;
    const float* brow = blankT + b * BSTRIDE;

    // skip-transition masks (multiplicative 0/1)
    const int tg0 = tgt[b * Sc + 2 * lane];
    const int tg1 = tgt[b * Sc + 2 * lane + 1];
    const int tgm = (lane > 0) ? tgt[b * Sc + 2 * lane - 1] : tg0;
    const float m1 = (lane > 0 && tg0 != tgm) ? 1.f : 0.f;  // j=4l+1 skip via alpha[4l-1]
    const float m3 = (tg1 != tg0) ? 1.f : 0.f;              // j=4l+3 skip via alpha[4l+1]
    const float sel = (lane == 63) ? 1.f : 0.f;             // state 256 gate

    const int steps = min(in_len[b], Tc) - 1;   // live steps: t = 1..steps

    // t = 0 init (values carry one 2^BOOST factor)
    const u32 p0 = p[lane];
    float a0 = (lane == 0) ? brow[0] : 0.f;
    float a1 = (lane == 0) ? bflo(p0) : 0.f;
    float a2 = 0.f, a3 = 0.f, a4 = 0.f;
    int e_acc = 0;

    u32 pk[32];
    const u32* pr = p + 64;                     // row t=1
#pragma unroll
    for (int d = 0; d < 32; ++d) pk[d] = pr[d * 64 + lane];
    const u32* pg = p + (size_t)33 * 64;        // refill source: row t+32 for t=1

    float blkc = brow[1 + lane];                // blanks for t = 1..64

#define RENORM() {                                                  \
        float m = fmaxf(fmaxf(fmaxf(a0, a1), fmaxf(a2, a3)), a4);   \
        m = wave_max_bcast(m);                                      \
        int e = (int)((__float_as_uint(m) >> 23) & 0xffu) - 127;    \
        float scale = __uint_as_float((u32)(127 - e) << 23);        \
        a0 *= scale; a1 *= scale; a2 *= scale;                      \
        a3 *= scale; a4 *= scale;                                   \
        e_acc += e; }

    // unmasked 16-step group; g = group index within superblock (0..3)
#define GROUP_N(g) {                                                \
        const int H = ((g) & 1) * 16;                               \
        const int BI = (g) * 16;                                    \
        _Pragma("unroll")                                           \
        for (int d = 0; d < 16; ++d) {                              \
            const u32 pv = pk[H + d];                               \
            pk[H + d] = pg[d * 64 + lane];                          \
            const float ebl = RLF(blkc, BI + d);                    \
            const float e1 = bflo(pv);                              \
            const float e3 = bfhi(pv);                              \
            const float sh = wave_shr1(a3);                         \
            const float s01 = a0 + a1;                              \
            const float s12 = a1 + a2;                              \
            const float s23 = a2 + a3;                              \
            const float n0 = ebl * (a0 + sh);                       \
            const float n1 = e1 * fmaf(m1, sh, s01);                \
            const float n3 = e3 * fmaf(m3, a1, s23);                \
            a4 = ebl * fmaf(sel, a3, a4);                           \
            a0 = n0; a1 = n1; a2 = ebl * s12; a3 = n3;              \
            if (d == 7 || d == 15) RENORM()                         \
        }                                                           \
        pg += 16 * 64; }

    // masked 16-step group (tail superblock)
#define GROUP_T(g) {                                                \
        const int H = ((g) & 1) * 16;                               \
        const int BI = (g) * 16;                                    \
        _Pragma("unroll")                                           \
        for (int d = 0; d < 16; ++d) {                              \
            const u32 pv = pk[H + d];                               \
            pk[H + d] = pg[d * 64 + lane];                          \
            const float ebl = RLF(blkc, BI + d);                    \
            const float e1 = bflo(pv);                              \
            const float e3 = bfhi(pv);                              \
            const float sh = wave_shr1(a3);                         \
            const float s01 = a0 + a1;                              \
            const float s12 = a1 + a2;                              \
            const float s23 = a2 + a3;                              \
            const float n0 = ebl * (a0 + sh);                       \
            const float n1 = e1 * fmaf(m1, sh, s01);                \
            const float n2 = ebl * s12;                             \
            const float n3 = e3 * fmaf(m3, a1, s23);                \
            const float n4 = ebl * fmaf(sel, a3, a4);               \
            const bool live = (t <= steps);                         \
            a0 = live ? n0 : a0; a1 = live ? n1 : a1;               \
            a2 = live ? n2 : a2; a3 = live ? n3 : a3;               \
            a4 = live ? n4 : a4;                                    \
            ++t;                                                    \
            if (d == 7 || d == 15) RENORM()                         \
        }                                                           \
        pg += 16 * 64; }

    const int nsb = steps >> 6;                 // full 64-step superblocks
    for (int sb = 0; sb < nsb; ++sb) {
        const float blkn = brow[(sb + 1) * 64 + 1 + lane];
        GROUP_N(0) GROUP_N(1) GROUP_N(2) GROUP_N(3)
        blkc = blkn;
    }
    // masked tail superblock (<= 64 live steps remain; renorms are
    // value-preserving on frozen alphas via e_acc accounting)
    int t = (nsb << 6) + 1;
    GROUP_T(0) GROUP_T(1) GROUP_T(2) GROUP_T(3)
#undef GROUP_N
#undef GROUP_T
#undef RENORM

    // terminal: ll = log(alpha[2tl] + alpha[2tl-1]) + ln2*(e_acc - BOOST*(steps+1))
    __shared__ float sa[257];
    sa[4 * lane + 0] = a0;
    sa[4 * lane + 1] = a1;
    sa[4 * lane + 2] = a2;
    sa[4 * lane + 3] = a3;
    if (lane == 63) sa[256] = a4;
    __syncthreads();
    if (lane == 0) {
        const int tl = tg_len[b];
        const int ei = 2 * tl;
        const float ssum = sa[ei] + sa[ei - 1];
        const float ll = __logf(ssum) +
                         LN2 * ((float)e_acc - (float)BOOST * (float)(steps + 1));
        atomicAdd(out, ll / (float)tl / (float)Bc);
    }
}

extern "C" void kernel_launch(void* const* d_in, const int* in_sizes, int n_in,
                              void* d_out, int out_size, void* d_ws, size_t ws_size,
                              hipStream_t stream) {
    const float* lp = (const float*)d_in[0];   // (T,B,V) fp32 log-softmax
    const int* tgt = (const int*)d_in[1];      // (B,S) int32
    const int* in_len = (const int*)d_in[2];   // (B,)
    const int* tg_len = (const int*)d_in[3];   // (B,)

    char* ws = (char*)d_ws;
    float* blankT = (float*)ws;                // Bc*BSTRIDE f32 = 72 KB
    u32* emitT = (u32*)(ws + 128 * 1024);      // Bc*Tc*64 u32 = 4 MB (+overread slack in ws)

    (void)hipMemsetAsync(d_out, 0, sizeof(float), stream);
    k_gather<<<dim3(Tc / (4 * NT), Bc), 256, 0, stream>>>(lp, tgt, emitT, blankT);
    k_ctc<<<Bc, 64, 0, stream>>>(emitT, blankT, tgt, in_len, tg_len, (float*)d_out);
}